// Round 1
// baseline (1707.645 us; speedup 1.0000x reference)
//
#include <hip/hip_runtime.h>

#define NSTEP 10

// ---------------------------------------------------------------------------
// Prep: transpose W1 [256][250] -> W1T [250][256], W2 [128][256] -> W2T [256][128]
// into workspace (needed for coalesced k-major streaming in the main kernel).
// ---------------------------------------------------------------------------
extern "C" __global__ void __launch_bounds__(256) snn_prep(
    const float* __restrict__ W1, const float* __restrict__ W2,
    float* __restrict__ W1T, float* __restrict__ W2T)
{
    int i0 = blockIdx.x * 256 + threadIdx.x;
    int stride = gridDim.x * 256;
    for (int idx = i0; idx < 250 * 256; idx += stride) {
        int k = idx >> 8;         // row of W1T
        int n = idx & 255;        // col of W1T
        W1T[idx] = W1[n * 250 + k];
    }
    for (int idx = i0; idx < 256 * 128; idx += stride) {
        int k = idx >> 7;
        int j = idx & 127;
        W2T[idx] = W2[j * 256 + k];
    }
}

// ---------------------------------------------------------------------------
// Main fused SNN kernel.
//
// One workgroup = 64 samples, 256 threads, all 10 timesteps fused.
// Thread maps:
//   st = t>>4  (16 groups), s0 = st*4   -> 4 samples per thread (shared by L1/L2)
//   L1: nt = t&15, n0 = nt*16           -> 16 layer-1 neurons per thread
//   L2: jt = t&15, j tiles jt*4 and 64+jt*4 -> 8 layer-2 neurons per thread
//   L3: sl3 = t&63, jr = t>>6           -> 4-way split over j for partials
//
// LDS layout (bytes):
//   [0,32768)     s1L  ushort[256][64]  spikes L1 as bf16 (exact {0,1}), XOR-swizzled cols
//   [32768,49152) s2L  ushort[128][64]  spikes L2, XOR-swizzled cols
//   [49152,65536) W2c  float[32][128]   W2T k-chunk staging buffer
//   [65536,69632) W3L  float[128][8]    W3 transposed+padded
//   [69632,74752) pL   float[4][5][64]  layer-3 partial sums
//   [74752,75284) bL   float[133]       b2[128] ++ b3[5]
// Prologue alias: xT float[250][68] @0 (68000 B) - dead before s1L/W3L written.
// ---------------------------------------------------------------------------
extern "C" __global__ void __launch_bounds__(256, 2) snn_main(
    const float* __restrict__ x,
    const float* __restrict__ b1,
    const float* __restrict__ b2g,
    const float* __restrict__ W3,
    const float* __restrict__ b3,
    const float* __restrict__ W1T,
    const float* __restrict__ W2T,
    float* __restrict__ out)
{
    __shared__ __align__(16) char ldsraw[75296];
    unsigned short* s1L = (unsigned short*)(ldsraw);
    unsigned short* s2L = (unsigned short*)(ldsraw + 32768);
    float* W2c = (float*)(ldsraw + 49152);
    float* W3L = (float*)(ldsraw + 65536);
    float* pL  = (float*)(ldsraw + 69632);
    float* bL  = (float*)(ldsraw + 74752);
    float* xT  = (float*)(ldsraw);   // prologue alias

    const int t  = threadIdx.x;
    const int st = t >> 4;
    const int s0 = st * 4;
    const int nt = t & 15;
    const int n0 = nt * 16;
    const int jt = t & 15;
    const int sBase = blockIdx.x * 64;

    // ---- prologue: stage x tile transposed (pad row to 68 floats) ----
    for (int i = t; i < 64 * 250; i += 256) {
        int sl = i / 250;
        int kl = i - sl * 250;
        xT[kl * 68 + sl] = x[(sBase + sl) * 250 + kl];
    }
    __syncthreads();

    // ---- cur1 = x @ W1.T  (bias added after dot, numpy-style) ----
    float cur1[16][4];
    #pragma unroll
    for (int i = 0; i < 16; ++i)
        #pragma unroll
        for (int j = 0; j < 4; ++j) cur1[i][j] = 0.0f;

    #pragma unroll 2
    for (int k = 0; k < 250; ++k) {
        float4 xa = *(const float4*)&xT[k * 68 + s0];
        float w[16];
        *(float4*)&w[0]  = *(const float4*)&W1T[k * 256 + n0];
        *(float4*)&w[4]  = *(const float4*)&W1T[k * 256 + n0 + 4];
        *(float4*)&w[8]  = *(const float4*)&W1T[k * 256 + n0 + 8];
        *(float4*)&w[12] = *(const float4*)&W1T[k * 256 + n0 + 12];
        const float* xs = &xa.x;
        #pragma unroll
        for (int i = 0; i < 16; ++i)
            #pragma unroll
            for (int j = 0; j < 4; ++j)
                cur1[i][j] = fmaf(w[i], xs[j], cur1[i][j]);
    }
    {
        float bb[16];
        *(float4*)&bb[0]  = *(const float4*)&b1[n0];
        *(float4*)&bb[4]  = *(const float4*)&b1[n0 + 4];
        *(float4*)&bb[8]  = *(const float4*)&b1[n0 + 8];
        *(float4*)&bb[12] = *(const float4*)&b1[n0 + 12];
        #pragma unroll
        for (int i = 0; i < 16; ++i)
            #pragma unroll
            for (int j = 0; j < 4; ++j)
                cur1[i][j] = __fadd_rn(cur1[i][j], bb[i]);
    }
    __syncthreads();   // xT dead; its region may now be reused

    // ---- stage W3 (transposed, padded to 8) and biases into LDS ----
    for (int idx = t; idx < 640; idx += 256) {
        int o = idx >> 7;          // 640 = 5*128, W3 is [5][128]
        int j = idx & 127;
        W3L[j * 8 + o] = W3[idx];
    }
    if (t < 128) bL[t] = b2g[t];
    if (t < 5)   bL[128 + t] = b3[t];
    __syncthreads();

    // ---- persistent state ----
    float m1[16][4];
    #pragma unroll
    for (int i = 0; i < 16; ++i)
        #pragma unroll
        for (int j = 0; j < 4; ++j) m1[i][j] = 0.0f;
    float m2[2][4][4];
    #pragma unroll
    for (int h = 0; h < 2; ++h)
        #pragma unroll
        for (int jj = 0; jj < 4; ++jj)
            #pragma unroll
            for (int ss = 0; ss < 4; ++ss) m2[h][jj][ss] = 0.0f;
    float m3[5], acc3[5];
    #pragma unroll
    for (int o = 0; o < 5; ++o) { m3[o] = 0.0f; acc3[o] = 0.0f; }

    const int xk1 = (nt & 7) << 3;   // s1L column swizzle for this thread's rows
    const int xk2 = (jt & 7) << 3;   // s2L column swizzle

    for (int stp = 0; stp < NSTEP; ++stp) {
        // ================= A: layer-1 LIF update + s1 -> LDS =================
        #pragma unroll
        for (int i = 0; i < 16; ++i) {
            unsigned int pk0 = 0, pk1 = 0;
            #pragma unroll
            for (int j = 0; j < 4; ++j) {
                float m = m1[i][j];
                float r = (m > 1.0f) ? 1.0f : 0.0f;
                m = __fsub_rn(__fadd_rn(__fmul_rn(0.9f, m), cur1[i][j]), r);
                m1[i][j] = m;
                unsigned int sv = (m > 1.0f) ? 0x3F80u : 0u;  // bf16 1.0 / 0.0
                if (j == 0) pk0 = sv;
                if (j == 1) pk0 |= sv << 16;
                if (j == 2) pk1 = sv;
                if (j == 3) pk1 |= sv << 16;
            }
            uint2 pk; pk.x = pk0; pk.y = pk1;
            *(uint2*)&s1L[(n0 + i) * 64 + (s0 ^ xk1)] = pk;
        }

        // ================= B: cur2 = s1 @ W2.T (8 chunks of 32 k) ============
        float a2[2][4][4];
        #pragma unroll
        for (int h = 0; h < 2; ++h)
            #pragma unroll
            for (int jj = 0; jj < 4; ++jj)
                #pragma unroll
                for (int ss = 0; ss < 4; ++ss) a2[h][jj][ss] = 0.0f;

        float4 wr0, wr1, wr2, wr3;
        wr0 = *(const float4*)(W2T + 0 * 1024 + t * 4);
        wr1 = *(const float4*)(W2T + 1 * 1024 + t * 4);
        wr2 = *(const float4*)(W2T + 2 * 1024 + t * 4);
        wr3 = *(const float4*)(W2T + 3 * 1024 + t * 4);

        for (int c = 0; c < 8; ++c) {
            __syncthreads();                    // prior readers of W2c/s1L done
            *(float4*)&W2c[0 * 1024 + t * 4] = wr0;
            *(float4*)&W2c[1 * 1024 + t * 4] = wr1;
            *(float4*)&W2c[2 * 1024 + t * 4] = wr2;
            *(float4*)&W2c[3 * 1024 + t * 4] = wr3;
            if (c < 7) {
                const float* src = W2T + (c + 1) * 4096;
                wr0 = *(const float4*)(src + 0 * 1024 + t * 4);
                wr1 = *(const float4*)(src + 1 * 1024 + t * 4);
                wr2 = *(const float4*)(src + 2 * 1024 + t * 4);
                wr3 = *(const float4*)(src + 3 * 1024 + t * 4);
            }
            __syncthreads();                    // W2c chunk ready
            #pragma unroll 4
            for (int kk = 0; kk < 32; ++kk) {
                const int k = c * 32 + kk;
                const float4 wa = *(const float4*)&W2c[kk * 128 + jt * 4];
                const float4 wb = *(const float4*)&W2c[kk * 128 + 64 + jt * 4];
                const uint2 sp =
                    *(const uint2*)&s1L[k * 64 + (s0 ^ (((k >> 4) & 7) << 3))];
                float fs[4];
                fs[0] = __uint_as_float(sp.x << 16);
                fs[1] = __uint_as_float(sp.x & 0xFFFF0000u);
                fs[2] = __uint_as_float(sp.y << 16);
                fs[3] = __uint_as_float(sp.y & 0xFFFF0000u);
                const float* wav = &wa.x;
                const float* wbv = &wb.x;
                #pragma unroll
                for (int jj = 0; jj < 4; ++jj)
                    #pragma unroll
                    for (int ss = 0; ss < 4; ++ss) {
                        a2[0][jj][ss] = fmaf(wav[jj], fs[ss], a2[0][jj][ss]);
                        a2[1][jj][ss] = fmaf(wbv[jj], fs[ss], a2[1][jj][ss]);
                    }
            }
        }

        // ================= C: layer-2 LIF update + s2 -> LDS =================
        #pragma unroll
        for (int h = 0; h < 2; ++h)
            #pragma unroll
            for (int jj = 0; jj < 4; ++jj) {
                const int j = h * 64 + jt * 4 + jj;
                const float bj = bL[j];
                unsigned int pk0 = 0, pk1 = 0;
                #pragma unroll
                for (int ss = 0; ss < 4; ++ss) {
                    float c2 = __fadd_rn(a2[h][jj][ss], bj);   // dot + b2
                    float m = m2[h][jj][ss];
                    float r = (m > 1.0f) ? 1.0f : 0.0f;
                    m = __fsub_rn(__fadd_rn(__fmul_rn(0.9f, m), c2), r);
                    m2[h][jj][ss] = m;
                    unsigned int sv = (m > 1.0f) ? 0x3F80u : 0u;
                    if (ss == 0) pk0 = sv;
                    if (ss == 1) pk0 |= sv << 16;
                    if (ss == 2) pk1 = sv;
                    if (ss == 3) pk1 |= sv << 16;
                }
                uint2 pk; pk.x = pk0; pk.y = pk1;
                *(uint2*)&s2L[j * 64 + (s0 ^ xk2)] = pk;
            }
        __syncthreads();   // s2 ready

        // ================= D: layer-3 partial dots ===========================
        {
            const int sl3 = t & 63;
            const int jr = t >> 6;
            float part[5] = {0.0f, 0.0f, 0.0f, 0.0f, 0.0f};
            #pragma unroll 4
            for (int jj = 0; jj < 32; ++jj) {
                const int j = jr * 32 + jj;
                const unsigned short sv =
                    s2L[j * 64 + (sl3 ^ (((j >> 2) & 7) << 3))];
                const float s2v = __uint_as_float(((unsigned int)sv) << 16);
                const float4 w3a = *(const float4*)&W3L[j * 8];
                const float  w3e = W3L[j * 8 + 4];
                part[0] = fmaf(w3a.x, s2v, part[0]);
                part[1] = fmaf(w3a.y, s2v, part[1]);
                part[2] = fmaf(w3a.z, s2v, part[2]);
                part[3] = fmaf(w3a.w, s2v, part[3]);
                part[4] = fmaf(w3e,   s2v, part[4]);
            }
            #pragma unroll
            for (int o = 0; o < 5; ++o)
                pL[(jr * 5 + o) * 64 + sl3] = part[o];
        }
        __syncthreads();   // partials ready

        // ================= E: layer-3 LIF update + spike count ===============
        if (t < 64) {
            #pragma unroll
            for (int o = 0; o < 5; ++o) {
                float c3 = pL[o * 64 + t];
                c3 += pL[(5 + o) * 64 + t];
                c3 += pL[(10 + o) * 64 + t];
                c3 += pL[(15 + o) * 64 + t];
                c3 = __fadd_rn(c3, bL[128 + o]);
                float m = m3[o];
                float r = (m > 1.0f) ? 1.0f : 0.0f;
                m = __fsub_rn(__fadd_rn(__fmul_rn(0.9f, m), c3), r);
                m3[o] = m;
                if (m > 1.0f) acc3[o] += 1.0f;
            }
        }
    }

    // ---- epilogue: write spike counts ----
    if (t < 64) {
        const int base = (sBase + t) * 5;
        #pragma unroll
        for (int o = 0; o < 5; ++o) out[base + o] = acc3[o];
    }
}

extern "C" void kernel_launch(void* const* d_in, const int* in_sizes, int n_in,
                              void* d_out, int out_size, void* d_ws, size_t ws_size,
                              hipStream_t stream) {
    const float* x  = (const float*)d_in[0];
    const float* W1 = (const float*)d_in[1];
    const float* b1 = (const float*)d_in[2];
    const float* W2 = (const float*)d_in[3];
    const float* b2 = (const float*)d_in[4];
    const float* W3 = (const float*)d_in[5];
    const float* b3 = (const float*)d_in[6];
    float* out = (float*)d_out;

    float* W1T = (float*)d_ws;            // 250*256 floats
    float* W2T = W1T + 250 * 256;         // 256*128 floats

    const int B = in_sizes[0] / 250;      // 131072
    const int nwg = B / 64;               // 2048

    snn_prep<<<128, 256, 0, stream>>>(W1, W2, W1T, W2T);
    snn_main<<<nwg, 256, 0, stream>>>(x, b1, b2, W3, b3, W1T, W2T, out);
}

// Round 2
// 1586.757 us; speedup vs baseline: 1.0762x; 1.0762x over previous
//
#include <hip/hip_runtime.h>

#define NSTEP 10

// ---------------------------------------------------------------------------
// Prep: transpose W1 [256][250] -> W1T [250][256], W2 [128][256] -> W2T [256][128]
// ---------------------------------------------------------------------------
extern "C" __global__ void __launch_bounds__(256) snn_prep(
    const float* __restrict__ W1, const float* __restrict__ W2,
    float* __restrict__ W1T, float* __restrict__ W2T)
{
    int i0 = blockIdx.x * 256 + threadIdx.x;
    int stride = gridDim.x * 256;
    for (int idx = i0; idx < 250 * 256; idx += stride) {
        int k = idx >> 8;
        int n = idx & 255;
        W1T[idx] = W1[n * 250 + k];
    }
    for (int idx = i0; idx < 256 * 128; idx += stride) {
        int k = idx >> 7;
        int j = idx & 127;
        W2T[idx] = W2[j * 256 + k];
    }
}

// ---------------------------------------------------------------------------
// Main fused SNN kernel. 64 samples/block, 256 threads, 10 steps fused.
//
// Thread maps (unchanged from round 1):
//   st = t>>4, s0 = st*4     -> 4 samples per thread
//   L1: nt = t&15, n0=nt*16  -> 16 layer-1 neurons/thread
//   L2: jt = t&15, j = {jt*4..+3, 64+jt*4..+3} -> 8 layer-2 neurons/thread
//   L3: sl3 = t&63, jr = t>>6
//
// Changes vs round 1:
//   - u8 spikes in LDS (exact {0,1}; v_cvt_f32_ubyte unpack) -> -24 KB LDS
//   - W2c chunk staging double-buffered -> 1 barrier/chunk (11/step vs 18)
//   - amdgpu_waves_per_eu(2,2): full 256-VGPR budget (occupancy is LDS-bound
//     at 2 blocks/CU regardless) -> eliminates the 71 MB/dispatch spill traffic
//
// LDS layout (bytes):
//   [0,16384)      s1L u8[256][64]   XOR-swizzled cols: byte = s ^ ((row>>4&15)<<2)
//   [16384,24576)  s2L u8[128][64]   byte = s ^ ((j>>2&15)<<2)
//   [24576,57344)  W2c f32 2x[32][128] double-buffered chunk staging
//   [57344,61440)  W3L f32[128][8]
//   [61440,66560)  pL  f32[20][64]
//   [66560,67092)  bL  f32[133]
// Prologue alias: xT f32[250][68] @0 (68000 B), dead after cur1.
// Total 68096 B -> 2 blocks/CU (136 KB of 160 KB).
// ---------------------------------------------------------------------------
extern "C" __global__ void
__attribute__((amdgpu_flat_work_group_size(256, 256), amdgpu_waves_per_eu(2, 2)))
snn_main(
    const float* __restrict__ x,
    const float* __restrict__ b1,
    const float* __restrict__ b2g,
    const float* __restrict__ W3,
    const float* __restrict__ b3,
    const float* __restrict__ W1T,
    const float* __restrict__ W2T,
    float* __restrict__ out)
{
    __shared__ __align__(16) char ldsraw[68096];
    unsigned char* s1Lb = (unsigned char*)(ldsraw);
    unsigned char* s2Lb = (unsigned char*)(ldsraw + 16384);
    float* W2c = (float*)(ldsraw + 24576);
    float* W3L = (float*)(ldsraw + 57344);
    float* pL  = (float*)(ldsraw + 61440);
    float* bL  = (float*)(ldsraw + 66560);
    float* xT  = (float*)(ldsraw);   // prologue alias

    const int t  = threadIdx.x;
    const int st = t >> 4;
    const int s0 = st * 4;
    const int nt = t & 15;
    const int n0 = nt * 16;
    const int jt = t & 15;
    const int sBase = blockIdx.x * 64;

    // ---- prologue: stage x tile transposed (row padded to 68 floats) ----
    for (int i = t; i < 64 * 250; i += 256) {
        int sl = i / 250;
        int kl = i - sl * 250;
        xT[kl * 68 + sl] = x[(sBase + sl) * 250 + kl];
    }
    __syncthreads();

    // ---- cur1 = x @ W1.T (bias after dot, numpy order; identical to R1) ----
    float cur1[16][4];
    #pragma unroll
    for (int i = 0; i < 16; ++i)
        #pragma unroll
        for (int j = 0; j < 4; ++j) cur1[i][j] = 0.0f;

    #pragma unroll 2
    for (int k = 0; k < 250; ++k) {
        float4 xa = *(const float4*)&xT[k * 68 + s0];
        float w[16];
        *(float4*)&w[0]  = *(const float4*)&W1T[k * 256 + n0];
        *(float4*)&w[4]  = *(const float4*)&W1T[k * 256 + n0 + 4];
        *(float4*)&w[8]  = *(const float4*)&W1T[k * 256 + n0 + 8];
        *(float4*)&w[12] = *(const float4*)&W1T[k * 256 + n0 + 12];
        const float* xs = &xa.x;
        #pragma unroll
        for (int i = 0; i < 16; ++i)
            #pragma unroll
            for (int j = 0; j < 4; ++j)
                cur1[i][j] = fmaf(w[i], xs[j], cur1[i][j]);
    }
    {
        float bb[16];
        *(float4*)&bb[0]  = *(const float4*)&b1[n0];
        *(float4*)&bb[4]  = *(const float4*)&b1[n0 + 4];
        *(float4*)&bb[8]  = *(const float4*)&b1[n0 + 8];
        *(float4*)&bb[12] = *(const float4*)&b1[n0 + 12];
        #pragma unroll
        for (int i = 0; i < 16; ++i)
            #pragma unroll
            for (int j = 0; j < 4; ++j)
                cur1[i][j] = __fadd_rn(cur1[i][j], bb[i]);
    }
    __syncthreads();   // xT dead

    // ---- stage W3 (transposed, padded) and biases ----
    for (int idx = t; idx < 640; idx += 256) {
        int o = idx >> 7;
        int j = idx & 127;
        W3L[j * 8 + o] = W3[idx];
    }
    if (t < 128) bL[t] = b2g[t];
    if (t < 5)   bL[128 + t] = b3[t];
    __syncthreads();

    // ---- persistent state ----
    float m1[16][4];
    #pragma unroll
    for (int i = 0; i < 16; ++i)
        #pragma unroll
        for (int j = 0; j < 4; ++j) m1[i][j] = 0.0f;
    float m2[2][4][4];
    #pragma unroll
    for (int h = 0; h < 2; ++h)
        #pragma unroll
        for (int jj = 0; jj < 4; ++jj)
            #pragma unroll
            for (int ss = 0; ss < 4; ++ss) m2[h][jj][ss] = 0.0f;
    float m3[5], acc3[5];
    #pragma unroll
    for (int o = 0; o < 5; ++o) { m3[o] = 0.0f; acc3[o] = 0.0f; }

    for (int stp = 0; stp < NSTEP; ++stp) {
        // ========== A: layer-1 LIF + s1 -> LDS (u8, swizzled) ==========
        #pragma unroll
        for (int i = 0; i < 16; ++i) {
            unsigned int pk = 0;
            #pragma unroll
            for (int j = 0; j < 4; ++j) {
                float m = m1[i][j];
                float r = (m > 1.0f) ? 1.0f : 0.0f;
                m = __fsub_rn(__fadd_rn(__fmul_rn(0.9f, m), cur1[i][j]), r);
                m1[i][j] = m;
                if (m > 1.0f) pk |= (1u << (8 * j));
            }
            *(unsigned int*)&s1Lb[(n0 + i) * 64 + (s0 ^ (nt << 2))] = pk;
        }

        // ========== B: cur2 = s1 @ W2.T (8 chunks, double-buffered) ==========
        float a2[2][4][4];
        #pragma unroll
        for (int h = 0; h < 2; ++h)
            #pragma unroll
            for (int jj = 0; jj < 4; ++jj)
                #pragma unroll
                for (int ss = 0; ss < 4; ++ss) a2[h][jj][ss] = 0.0f;

        // prefetch chunk 0
        float4 wr0 = *(const float4*)(W2T + 0 * 1024 + t * 4);
        float4 wr1 = *(const float4*)(W2T + 1 * 1024 + t * 4);
        float4 wr2 = *(const float4*)(W2T + 2 * 1024 + t * 4);
        float4 wr3 = *(const float4*)(W2T + 3 * 1024 + t * 4);

        __syncthreads();   // B1: s1 ready; W2c bufs' prior readers retired

        for (int c = 0; c < 8; ++c) {
            float* buf = W2c + ((c & 1) << 12);   // 4096 floats per buffer
            *(float4*)&buf[0 * 1024 + t * 4] = wr0;
            *(float4*)&buf[1 * 1024 + t * 4] = wr1;
            *(float4*)&buf[2 * 1024 + t * 4] = wr2;
            *(float4*)&buf[3 * 1024 + t * 4] = wr3;
            if (c < 7) {
                const float* src = W2T + (c + 1) * 4096;
                wr0 = *(const float4*)(src + 0 * 1024 + t * 4);
                wr1 = *(const float4*)(src + 1 * 1024 + t * 4);
                wr2 = *(const float4*)(src + 2 * 1024 + t * 4);
                wr3 = *(const float4*)(src + 3 * 1024 + t * 4);
            }
            __syncthreads();   // chunk c staged (1 barrier per chunk)

            #pragma unroll
            for (int half = 0; half < 2; ++half) {
                const unsigned char* s1k =
                    s1Lb + c * 2048 + half * 1024 +
                    (s0 ^ ((((c << 1) + half) & 15) << 2));
                const float* wk = buf + half * 2048 + jt * 4;
                #pragma unroll 8
                for (int kk = 0; kk < 16; ++kk) {
                    const float4 wa = *(const float4*)(wk + kk * 128);
                    const float4 wb = *(const float4*)(wk + kk * 128 + 64);
                    const unsigned int sp = *(const unsigned int*)(s1k + kk * 64);
                    float fsv[4];
                    fsv[0] = (float)(sp & 0xFFu);
                    fsv[1] = (float)((sp >> 8) & 0xFFu);
                    fsv[2] = (float)((sp >> 16) & 0xFFu);
                    fsv[3] = (float)(sp >> 24);
                    const float* wav = &wa.x;
                    const float* wbv = &wb.x;
                    #pragma unroll
                    for (int jj = 0; jj < 4; ++jj)
                        #pragma unroll
                        for (int ss = 0; ss < 4; ++ss) {
                            a2[0][jj][ss] = fmaf(wav[jj], fsv[ss], a2[0][jj][ss]);
                            a2[1][jj][ss] = fmaf(wbv[jj], fsv[ss], a2[1][jj][ss]);
                        }
                }
            }
        }

        // ========== C: layer-2 LIF + s2 -> LDS (u8, swizzled) ==========
        #pragma unroll
        for (int h = 0; h < 2; ++h)
            #pragma unroll
            for (int jj = 0; jj < 4; ++jj) {
                const int j = h * 64 + jt * 4 + jj;
                const float bj = bL[j];
                unsigned int pk = 0;
                #pragma unroll
                for (int ss = 0; ss < 4; ++ss) {
                    float c2 = __fadd_rn(a2[h][jj][ss], bj);
                    float m = m2[h][jj][ss];
                    float r = (m > 1.0f) ? 1.0f : 0.0f;
                    m = __fsub_rn(__fadd_rn(__fmul_rn(0.9f, m), c2), r);
                    m2[h][jj][ss] = m;
                    if (m > 1.0f) pk |= (1u << (8 * ss));
                }
                *(unsigned int*)&s2Lb[j * 64 + (s0 ^ (jt << 2))] = pk;
            }
        __syncthreads();   // s2 ready

        // ========== D: layer-3 partial dots ==========
        {
            const int sl3 = t & 63;
            const int jr = t >> 6;
            float part[5] = {0.0f, 0.0f, 0.0f, 0.0f, 0.0f};
            #pragma unroll 4
            for (int jj = 0; jj < 32; ++jj) {
                const int j = jr * 32 + jj;
                const int off = j * 64 +
                    (((sl3 & ~3) ^ (((j >> 2) & 15) << 2)) | (sl3 & 3));
                const float s2v = (float)s2Lb[off];
                const float4 w3a = *(const float4*)&W3L[j * 8];
                const float  w3e = W3L[j * 8 + 4];
                part[0] = fmaf(w3a.x, s2v, part[0]);
                part[1] = fmaf(w3a.y, s2v, part[1]);
                part[2] = fmaf(w3a.z, s2v, part[2]);
                part[3] = fmaf(w3a.w, s2v, part[3]);
                part[4] = fmaf(w3e,   s2v, part[4]);
            }
            #pragma unroll
            for (int o = 0; o < 5; ++o)
                pL[(jr * 5 + o) * 64 + sl3] = part[o];
        }
        __syncthreads();   // partials ready

        // ========== E: layer-3 LIF + spike count ==========
        if (t < 64) {
            #pragma unroll
            for (int o = 0; o < 5; ++o) {
                float c3 = pL[o * 64 + t];
                c3 += pL[(5 + o) * 64 + t];
                c3 += pL[(10 + o) * 64 + t];
                c3 += pL[(15 + o) * 64 + t];
                c3 = __fadd_rn(c3, bL[128 + o]);
                float m = m3[o];
                float r = (m > 1.0f) ? 1.0f : 0.0f;
                m = __fsub_rn(__fadd_rn(__fmul_rn(0.9f, m), c3), r);
                m3[o] = m;
                if (m > 1.0f) acc3[o] += 1.0f;
            }
        }
    }

    // ---- epilogue ----
    if (t < 64) {
        const int base = (sBase + t) * 5;
        #pragma unroll
        for (int o = 0; o < 5; ++o) out[base + o] = acc3[o];
    }
}

extern "C" void kernel_launch(void* const* d_in, const int* in_sizes, int n_in,
                              void* d_out, int out_size, void* d_ws, size_t ws_size,
                              hipStream_t stream) {
    const float* x  = (const float*)d_in[0];
    const float* W1 = (const float*)d_in[1];
    const float* b1 = (const float*)d_in[2];
    const float* W2 = (const float*)d_in[3];
    const float* b2 = (const float*)d_in[4];
    const float* W3 = (const float*)d_in[5];
    const float* b3 = (const float*)d_in[6];
    float* out = (float*)d_out;

    float* W1T = (float*)d_ws;            // 250*256 floats
    float* W2T = W1T + 250 * 256;         // 256*128 floats

    const int B = in_sizes[0] / 250;      // 131072
    const int nwg = B / 64;               // 2048

    snn_prep<<<128, 256, 0, stream>>>(W1, W2, W1T, W2T);
    snn_main<<<nwg, 256, 0, stream>>>(x, b1, b2, W3, b3, W1T, W2T, out);
}